// Round 32
// baseline (61.016 us; speedup 1.0000x reference)
//
#include <hip/hip_runtime.h>
#include <hip/hip_bf16.h>
#include <cstdint>

// MoE MLP fused forward. T=512, K=2 slots, E=32, H=512, I=512 (2I=1024).
// DEVICE DTYPES (probe-verified r20-r22): f32 tensors with bf16-exact values;
// output = full 262144 x f32 at d_out.
//
// r31 (glds staging): 59.3us — first real gain in 5 rounds; kernels now below
// the 39us fill-noise floor. Remaining gap vs ~25-30us traffic floor is
// residency: 48KB LDS -> 3 blocks/CU. r32: 32-row x K128 tiles (32KB LDS ->
// 5 blocks/CU, 2x blocks); wave w owns cols (w&1)*16, m-tile (w>>1)*16.
// Partial buffers + fixed-order sums (no atomics) -> bitwise deterministic.

#define MOE_E 32
#define MOE_H 512
#define MOE_I 512
#define MOE_2I 1024
#define MOE_CAP 1024

typedef __attribute__((ext_vector_type(8))) short s16x8;   // 8 bf16
typedef __attribute__((ext_vector_type(4))) float f32x4;   // 4 f32 acc

#define GLDS16(g, l)  __builtin_amdgcn_global_load_lds(                        \
    (const __attribute__((address_space(1))) unsigned int*)(g),                \
    (__attribute__((address_space(3))) unsigned int*)(l), 16, 0, 0)

__device__ __forceinline__ s16x8 pack8(float4 f0, float4 f1) {
    union { unsigned int u[4]; s16x8 v; } r;
    r.u[0] = (__float_as_uint(f0.y) & 0xFFFF0000u) | (__float_as_uint(f0.x) >> 16);
    r.u[1] = (__float_as_uint(f0.w) & 0xFFFF0000u) | (__float_as_uint(f0.z) >> 16);
    r.u[2] = (__float_as_uint(f1.y) & 0xFFFF0000u) | (__float_as_uint(f1.x) >> 16);
    r.u[3] = (__float_as_uint(f1.w) & 0xFFFF0000u) | (__float_as_uint(f1.z) >> 16);
    return r.v;
}

// ---------------- route: bucket (token,slot) pairs by expert ----------------
__global__ __launch_bounds__(1024) void moe_route(const int* __restrict__ idx,
                                                  int* __restrict__ cnt,
                                                  int* __restrict__ lists) {
    __shared__ int scnt[MOE_E];
    const int p = threadIdx.x;
    if (p < MOE_E) scnt[p] = 0;
    __syncthreads();
    int e = idx[p];
    e = (e < 0) ? 0 : (e > MOE_E - 1 ? MOE_E - 1 : e);
    const int pos = atomicAdd(&scnt[e], 1);
    lists[e * MOE_CAP + pos] = p;
    __syncthreads();
    if (p < MOE_E) cnt[p] = scnt[p];
}

// ---- mlp1 partial (MFMA, glds): grid (32, E, 4=kz), 256 thr = 4 waves. ----
// Block: 32 w1-rows x K-chunk 128 (LDS 32KB -> 5 blocks/CU). Wave w: cols
// (w&1)*16, m-tile (w>>1)*16. Units [q][r]: u=q*32+r, floats u*4..u*4+3.
__global__ __launch_bounds__(256) void moe_mlp1(
    const float* __restrict__ x, const float* __restrict__ w1,
    const float* __restrict__ b1, const int* __restrict__ cnt,
    const int* __restrict__ lists, float* __restrict__ t1p) {
    __shared__ float Bs[1024 * 4];   // 32 quads x 32 rows
    __shared__ float As[1024 * 4];   // 32 quads x 32 tokens
    const int e = blockIdx.y;
    const int ne = cnt[e];
    if (ne == 0) return;
    const int kz = blockIdx.z;
    const int tid  = threadIdx.x;
    const int lane = tid & 63;
    const int wave = tid >> 6;
    const int n16  = lane & 15;
    const int k8   = lane >> 4;
    const int colw = (wave & 1) * 16 + n16;                // 0..31 within tile
    const int mw   = (wave >> 1) * 16;                     // 0 or 16
    const int* lst = lists + e * MOE_CAP;
    const int cg = blockIdx.x * 32 + colw;                 // w1 row / t1 col
    const float bv = (kz == 0) ? b1[e * MOE_2I + cg] : 0.0f;
    const float* wbase = w1 + ((size_t)e * MOE_2I + blockIdx.x * 32) * MOE_H
                         + kz * 128;
    float* t1 = t1p + (size_t)kz * MOE_CAP * MOE_2I;

    // Stage Bs once: 1024 units, 4 glds/thread. unit u: q=u>>5, r=u&31.
    #pragma unroll
    for (int j = 0; j < 4; ++j) {
        const int u = (j * 4 + wave) * 64 + lane;
        const int q = u >> 5, r = u & 31;
        GLDS16(wbase + (size_t)r * MOE_H + q * 4, Bs + (size_t)(j * 4 + wave) * 256);
    }

    for (int m0 = 0; m0 < ne; m0 += 32) {
        __syncthreads();   // prior readers done (also orders Bs first iter)
        #pragma unroll
        for (int j = 0; j < 4; ++j) {
            const int u = (j * 4 + wave) * 64 + lane;
            const int q = u >> 5, r = u & 31;
            const int pm = lst[min(m0 + r, ne - 1)];
            GLDS16(x + (size_t)(pm >> 1) * MOE_H + kz * 128 + q * 4,
                   As + (size_t)(j * 4 + wave) * 256);
        }
        __syncthreads();   // vmcnt drain: Bs + As visible

        f32x4 acc = {0.f, 0.f, 0.f, 0.f};
        #pragma unroll
        for (int ks = 0; ks < 4; ++ks) {
            const int qB = ks * 8 + k8 * 2;
            const float4 B0 = *(const float4*)(Bs + 4 * (qB * 32 + colw));
            const float4 B1 = *(const float4*)(Bs + 4 * ((qB + 1) * 32 + colw));
            const float4 A0 = *(const float4*)(As + 4 * (qB * 32 + mw + n16));
            const float4 A1 = *(const float4*)(As + 4 * ((qB + 1) * 32 + mw + n16));
            acc = __builtin_amdgcn_mfma_f32_16x16x32_bf16(
                pack8(A0, A1), pack8(B0, B1), acc, 0, 0, 0);
        }
        const int mend = ne - m0;
        #pragma unroll
        for (int q = 0; q < 4; ++q) {
            const int mrow = mw + k8 * 4 + q;              // D: row=(l>>4)*4+q
            if (mrow < mend) {
                const int p = lst[m0 + mrow];
                t1[(size_t)p * MOE_2I + cg] = acc[q] + bv;
            }
        }
    }
}

// ---- swiglu: t1 = sum of 4 partials; even col gate, odd lin -> hbuf f32 ----
__global__ __launch_bounds__(256) void moe_swiglu(
    const float* __restrict__ t1p, float* __restrict__ hbuf) {
    const int tid  = threadIdx.x;
    const int pair = blockIdx.x * 2 + (tid >> 7);    // 512 blocks x 2 pairs
    const int i0   = (tid & 127) * 4;
    float4 s0 = {0.f, 0.f, 0.f, 0.f}, s1 = {0.f, 0.f, 0.f, 0.f};
    #pragma unroll
    for (int kzi = 0; kzi < 4; ++kzi) {
        const float* b = t1p + (size_t)kzi * MOE_CAP * MOE_2I
                       + (size_t)pair * MOE_2I + i0 * 2;
        const float4 v0 = *(const float4*)b;
        const float4 v1 = *(const float4*)(b + 4);
        s0.x += v0.x; s0.y += v0.y; s0.z += v0.z; s0.w += v0.w;
        s1.x += v1.x; s1.y += v1.y; s1.z += v1.z; s1.w += v1.w;
    }
    float g0 = s0.x, l0 = s0.y, g1 = s0.z, l1 = s0.w;
    float g2 = s1.x, l2 = s1.y, g3 = s1.z, l3 = s1.w;
    g0 = fminf(g0, 7.0f); l0 = fminf(fmaxf(l0, -7.0f), 7.0f);
    g1 = fminf(g1, 7.0f); l1 = fminf(fmaxf(l1, -7.0f), 7.0f);
    g2 = fminf(g2, 7.0f); l2 = fminf(fmaxf(l2, -7.0f), 7.0f);
    g3 = fminf(g3, 7.0f); l3 = fminf(fmaxf(l3, -7.0f), 7.0f);
    float4 h;
    h.x = g0 / (1.0f + expf(-1.702f * g0)) * (l0 + 1.0f);
    h.y = g1 / (1.0f + expf(-1.702f * g1)) * (l1 + 1.0f);
    h.z = g2 / (1.0f + expf(-1.702f * g2)) * (l2 + 1.0f);
    h.w = g3 / (1.0f + expf(-1.702f * g3)) * (l3 + 1.0f);
    *(float4*)(hbuf + (size_t)pair * MOE_I + i0) = h;
}

// ---- mlp2 partial (MFMA, glds): grid (16, E, 4=kz). 32-row tiles. ----
__global__ __launch_bounds__(256) void moe_mlp2(
    const float* __restrict__ hbuf, const float* __restrict__ w2,
    const float* __restrict__ b2, const int* __restrict__ cnt,
    const int* __restrict__ lists, float* __restrict__ pop) {
    __shared__ float Bs[1024 * 4];
    __shared__ float As[1024 * 4];
    const int e = blockIdx.y;
    const int ne = cnt[e];
    if (ne == 0) return;
    const int kz = blockIdx.z;
    const int tid  = threadIdx.x;
    const int lane = tid & 63;
    const int wave = tid >> 6;
    const int n16  = lane & 15;
    const int k8   = lane >> 4;
    const int colw = (wave & 1) * 16 + n16;
    const int mw   = (wave >> 1) * 16;
    const int* lst = lists + e * MOE_CAP;
    const int c = blockIdx.x * 32 + colw;                  // out col 0..511
    const float bv = (kz == 0) ? b2[e * MOE_H + c] : 0.0f;
    const float* wbase = w2 + ((size_t)e * MOE_H + blockIdx.x * 32) * MOE_I
                         + kz * 128;
    float* po = pop + (size_t)kz * MOE_CAP * MOE_H;

    #pragma unroll
    for (int j = 0; j < 4; ++j) {
        const int u = (j * 4 + wave) * 64 + lane;
        const int q = u >> 5, r = u & 31;
        GLDS16(wbase + (size_t)r * MOE_I + q * 4, Bs + (size_t)(j * 4 + wave) * 256);
    }

    for (int m0 = 0; m0 < ne; m0 += 32) {
        __syncthreads();
        #pragma unroll
        for (int j = 0; j < 4; ++j) {
            const int u = (j * 4 + wave) * 64 + lane;
            const int q = u >> 5, r = u & 31;
            const int pm = lst[min(m0 + r, ne - 1)];
            GLDS16(hbuf + (size_t)pm * MOE_I + kz * 128 + q * 4,
                   As + (size_t)(j * 4 + wave) * 256);
        }
        __syncthreads();

        f32x4 acc = {0.f, 0.f, 0.f, 0.f};
        #pragma unroll
        for (int ks = 0; ks < 4; ++ks) {
            const int qB = ks * 8 + k8 * 2;
            const float4 B0 = *(const float4*)(Bs + 4 * (qB * 32 + colw));
            const float4 B1 = *(const float4*)(Bs + 4 * ((qB + 1) * 32 + colw));
            const float4 A0 = *(const float4*)(As + 4 * (qB * 32 + mw + n16));
            const float4 A1 = *(const float4*)(As + 4 * ((qB + 1) * 32 + mw + n16));
            acc = __builtin_amdgcn_mfma_f32_16x16x32_bf16(
                pack8(A0, A1), pack8(B0, B1), acc, 0, 0, 0);
        }
        const int mend = ne - m0;
        #pragma unroll
        for (int q = 0; q < 4; ++q) {
            const int mrow = mw + k8 * 4 + q;
            if (mrow < mend) {
                const int p = lst[m0 + mrow];
                po[(size_t)p * MOE_H + c] = acc[q] + bv;
            }
        }
    }
}

// ---- combine: out[t,c] = ew0*SUM4 pop[.,2t,c] + ew1*SUM4 pop[.,2t+1,c] ----
__global__ __launch_bounds__(256) void MoEMLPFused_74191265071207_kernel(
    const float* __restrict__ pop, const float* __restrict__ ew,
    float* __restrict__ out) {
    const int o = blockIdx.x * 256 + threadIdx.x;   // < 262144
    const int t = o >> 9;
    const int c = o & 511;
    float s0 = 0.f, s1 = 0.f;
    #pragma unroll
    for (int kzi = 0; kzi < 4; ++kzi) {
        const float* pb = pop + (size_t)kzi * MOE_CAP * MOE_H;
        s0 += pb[(size_t)(2 * t + 0) * MOE_H + c];
        s1 += pb[(size_t)(2 * t + 1) * MOE_H + c];
    }
    out[o] = ew[2 * t + 0] * s0 + ew[2 * t + 1] * s1;
}

extern "C" void kernel_launch(void* const* d_in, const int* in_sizes, int n_in,
                              void* d_out, int out_size, void* d_ws, size_t ws_size,
                              hipStream_t stream) {
    const float* x   = (const float*)d_in[0];
    const int*   idx = (const int*)d_in[1];
    const float* ew  = (const float*)d_in[2];
    const float* w1  = (const float*)d_in[3];
    const float* b1  = (const float*)d_in[4];
    const float* w2  = (const float*)d_in[5];
    const float* b2  = (const float*)d_in[6];
    float* out = (float*)d_out;

    // ws: cnt 256B | lists 128KB | t1p 4x4MB | hbuf 2MB | pop 4x2MB (~26.2MB)
    char* ws = (char*)d_ws;
    int* cnt    = (int*)ws;
    int* lists  = (int*)(ws + 256);
    float* t1p  = (float*)(ws + 256 + MOE_E * MOE_CAP * 4);
    float* hbuf = t1p + 4u * MOE_CAP * MOE_2I;
    float* pop  = hbuf + (size_t)MOE_CAP * MOE_I;

    moe_route<<<1, 1024, 0, stream>>>(idx, cnt, lists);
    moe_mlp1<<<dim3(32, MOE_E, 4), 256, 0, stream>>>(x, w1, b1, cnt, lists, t1p);
    moe_swiglu<<<512, 256, 0, stream>>>(t1p, hbuf);
    moe_mlp2<<<dim3(16, MOE_E, 4), 256, 0, stream>>>(hbuf, w2, b2, cnt, lists, pop);
    MoEMLPFused_74191265071207_kernel<<<(512 * MOE_H) / 256, 256, 0, stream>>>(
        pop, ew, out);
}